// Round 6
// baseline (300.585 us; speedup 1.0000x reference)
//
#include <hip/hip_runtime.h>

#define I_DIM 28
#define H_DIM 64
#define T_DIM 128
#define B_DIM 4096
#define OUT_DIM 10
#define MB 16         // batch rows per block = full MFMA N
#define NTHREADS 512  // 8 waves: wave = (gp, grp); gp=gate-pair, grp=unit-group

typedef __attribute__((ext_vector_type(8))) short bf16x8;
typedef __attribute__((ext_vector_type(4))) float f32x4;
typedef __attribute__((ext_vector_type(4))) unsigned u32x4;

__device__ __forceinline__ unsigned f2bf_rne(float f) {
    unsigned u = __builtin_bit_cast(unsigned, f);
    return (u + 0x7FFFu + ((u >> 16) & 1u)) >> 16;
}
__device__ __forceinline__ float bfbits2f(unsigned b16) {
    return __builtin_bit_cast(float, b16 << 16);
}
__device__ __forceinline__ unsigned ftrunc_bf(float f) {
    return __builtin_bit_cast(unsigned, f) >> 16;
}

__device__ __forceinline__ void split_frag(const float* v, bf16x8& hi, bf16x8& lo) {
    unsigned hb[8], lb[8];
    #pragma unroll
    for (int j = 0; j < 8; ++j) {
        hb[j] = f2bf_rne(v[j]);
        float rem = v[j] - bfbits2f(hb[j]);
        lb[j] = ftrunc_bf(rem);
    }
    u32x4 hw, lw;
    #pragma unroll
    for (int i = 0; i < 4; ++i) {
        hw[i] = (hb[2*i+1] << 16) | (hb[2*i] & 0xFFFFu);
        lw[i] = (lb[2*i+1] << 16) | (lb[2*i] & 0xFFFFu);
    }
    hi = __builtin_bit_cast(bf16x8, hw);
    lo = __builtin_bit_cast(bf16x8, lw);
}

__device__ __forceinline__ float fast_rcp(float v) { return __builtin_amdgcn_rcpf(v); }
__device__ __forceinline__ float sigmoid_f(float v) { return fast_rcp(1.0f + __expf(-v)); }
__device__ __forceinline__ float tanh_f(float v) {
    float e = __expf(2.0f * v);
    return 1.0f - 2.0f * fast_rcp(e + 1.0f);
}

#define MFMA(A, B, C) __builtin_amdgcn_mfma_f32_16x16x32_bf16((A), (B), (C), 0, 0, 0)

__global__ __launch_bounds__(NTHREADS, 1)
void lstm_mfma_kernel(const float* __restrict__ x,
                      const float* __restrict__ W_ih,
                      const float* __restrict__ W_hh,
                      const float* __restrict__ b_ih,
                      const float* __restrict__ b_hh,
                      const float* __restrict__ W_out,
                      const float* __restrict__ b_out,
                      float* __restrict__ out)
{
    const int tid  = threadIdx.x;
    const int wv   = tid >> 6;        // 0..7
    const int grp  = wv & 3;          // unit-group: units 16*grp .. 16*grp+15
    const int gp   = wv >> 2;         // gate pair: 0 -> {i,f}, 1 -> {g,o}
    const int lane = tid & 63;
    const int q    = lane >> 4;
    const int cm   = lane & 15;       // batch col
    const int b0   = blockIdx.x * MB;

    // h state, pre-split hi/lo, B-frag order (same layout as R5, verified)
    __shared__ __align__(16) unsigned hfr_hi[2][2][256];
    __shared__ __align__(16) unsigned hfr_lo[2][2][256];
    // gate exchange: [gp][grp][gg][lane] float2 (contiguous b64, conflict-free)
    __shared__ __align__(16) float2 xch[2][4][2][64];

    // ---- resident A-frags: wave (gp,grp), gg in {0,1} -> gate 2gp+gg
    bf16x8 Whh_hi[2][2], Whh_lo[2][2], Wih_hi[2], Wih_lo[2];
    f32x4  bias_c[2];
    #pragma unroll
    for (int gg = 0; gg < 2; ++gg) {
        const int row = (2 * gp + gg) * H_DIM + grp * 16 + cm;
        #pragma unroll
        for (int kt = 0; kt < 2; ++kt) {
            const float* wr = W_hh + row * H_DIM + kt * 32 + q * 8;
            float wt[8];
            float4 wa = *(const float4*)wr;
            float4 wb = *(const float4*)(wr + 4);
            wt[0]=wa.x; wt[1]=wa.y; wt[2]=wa.z; wt[3]=wa.w;
            wt[4]=wb.x; wt[5]=wb.y; wt[6]=wb.z; wt[7]=wb.w;
            split_frag(wt, Whh_hi[gg][kt], Whh_lo[gg][kt]);
        }
        {
            const float* ir = W_ih + row * I_DIM + q * 8;
            float wt[8];
            float4 ia = *(const float4*)ir;
            wt[0]=ia.x; wt[1]=ia.y; wt[2]=ia.z; wt[3]=ia.w;
            if (q < 3) {
                float4 ib = *(const float4*)(ir + 4);
                wt[4]=ib.x; wt[5]=ib.y; wt[6]=ib.z; wt[7]=ib.w;
            } else { wt[4]=0.f; wt[5]=0.f; wt[6]=0.f; wt[7]=0.f; }
            split_frag(wt, Wih_hi[gg], Wih_lo[gg]);
        }
        #pragma unroll
        for (int r = 0; r < 4; ++r) {
            const int brow = (2 * gp + gg) * H_DIM + grp * 16 + 4 * q + r;
            bias_c[gg][r] = b_ih[brow] + b_hh[brow];
        }
    }

    // zero h(0) (buf 0); harmless to zero both kt halves
    for (int i = tid; i < 512; i += NTHREADS) {
        (&hfr_hi[0][0][0])[i] = 0u;
        (&hfr_lo[0][0][0])[i] = 0u;
    }

    auto load_x = [&](int t, float4& xa, float4& xb) {
        const float* p = x + ((size_t)(b0 + cm) * T_DIM + t) * I_DIM + q * 8;
        xa = *(const float4*)p;
        if (q < 3) xb = *(const float4*)(p + 4);
        else       xb = float4{0.f, 0.f, 0.f, 0.f};
    };

    // prologue: xw(0)
    f32x4 xw_t[2];
    {
        float4 xa, xb;
        load_x(0, xa, xb);
        float xt[8];
        xt[0]=xa.x; xt[1]=xa.y; xt[2]=xa.z; xt[3]=xa.w;
        xt[4]=xb.x; xt[5]=xb.y; xt[6]=xb.z; xt[7]=xb.w;
        bf16x8 Xhi, Xlo;
        split_frag(xt, Xhi, Xlo);
        #pragma unroll
        for (int gg = 0; gg < 2; ++gg) {
            f32x4 a = MFMA(Wih_hi[gg], Xhi, bias_c[gg]);
            a = MFMA(Wih_lo[gg], Xhi, a);
            a = MFMA(Wih_hi[gg], Xlo, a);
            xw_t[gg] = a;
        }
    }

    float c_st[2] = {0.f, 0.f};      // cells (rows 4q+2gp, 4q+2gp+1, col cm)
    const int mr = 2 * gp;           // my row half base
    const int pr = 2 - 2 * gp;       // partner's row half base
    // h write dword for unit pair u0 = grp*16 + 4q + 2gp
    const int ktw = grp >> 1;
    const int hdw = ((2 * (grp & 1) + (q >> 1)) * 16 + cm) * 4 + 2 * (q & 1) + gp;

    __syncthreads();   // zeros visible

    for (int t = 0; t < T_DIM; ++t) {
        const int rb = t & 1, wb = rb ^ 1;

        // issue x(t+1) loads early
        float4 xa_n, xb_n;
        load_x(t + 1 < T_DIM ? t + 1 : t, xa_n, xb_n);

        // h(t) B-frags
        bf16x8 Hhi0 = __builtin_bit_cast(bf16x8, *(u32x4*)&hfr_hi[rb][0][lane * 4]);
        bf16x8 Hhi1 = __builtin_bit_cast(bf16x8, *(u32x4*)&hfr_hi[rb][1][lane * 4]);
        bf16x8 Hlo0 = __builtin_bit_cast(bf16x8, *(u32x4*)&hfr_lo[rb][0][lane * 4]);
        bf16x8 Hlo1 = __builtin_bit_cast(bf16x8, *(u32x4*)&hfr_lo[rb][1][lane * 4]);

        // recurrent GEMM: 2 chains of 6, C-init = xw(t) (bias folded)
        f32x4 acc[2];
        #pragma unroll
        for (int gg = 0; gg < 2; ++gg) {
            f32x4 a = MFMA(Whh_hi[gg][0], Hhi0, xw_t[gg]);
            a = MFMA(Whh_hi[gg][1], Hhi1, a);
            a = MFMA(Whh_lo[gg][0], Hhi0, a);
            a = MFMA(Whh_lo[gg][1], Hhi1, a);
            a = MFMA(Whh_hi[gg][0], Hlo0, a);
            a = MFMA(Whh_hi[gg][1], Hlo1, a);
            acc[gg] = a;
        }

        // xw(t+1): overlaps exchange/update latency
        {
            float xt[8];
            xt[0]=xa_n.x; xt[1]=xa_n.y; xt[2]=xa_n.z; xt[3]=xa_n.w;
            xt[4]=xb_n.x; xt[5]=xb_n.y; xt[6]=xb_n.z; xt[7]=xb_n.w;
            bf16x8 Xhi, Xlo;
            split_frag(xt, Xhi, Xlo);
            #pragma unroll
            for (int gg = 0; gg < 2; ++gg) {
                f32x4 a = MFMA(Wih_hi[gg], Xhi, bias_c[gg]);
                a = MFMA(Wih_lo[gg], Xhi, a);
                a = MFMA(Wih_hi[gg], Xlo, a);
                xw_t[gg] = a;
            }
        }

        // publish partner-half gate values (contiguous b64 per wave)
        xch[gp][grp][0][lane] = float2{acc[0][pr], acc[0][pr + 1]};
        xch[gp][grp][1][lane] = float2{acc[1][pr], acc[1][pr + 1]};
        __syncthreads();   // exchange visible

        // read partner gates for my half rows
        float2 pg0 = xch[1 - gp][grp][0][lane];
        float2 pg1 = xch[1 - gp][grp][1][lane];

        // update 2 cells: rows 4q + mr + rr, col cm
        unsigned hw = 0, lw = 0;
        #pragma unroll
        for (int rr = 0; rr < 2; ++rr) {
            float own0 = acc[0][mr + rr];
            float own1 = acc[1][mr + rr];
            float p0 = rr ? pg0.y : pg0.x;
            float p1 = rr ? pg1.y : pg1.x;
            float iv, fv, gv, ov;
            if (gp == 0) { iv = own0; fv = own1; gv = p0; ov = p1; }
            else         { gv = own0; ov = own1; iv = p0; fv = p1; }
            float ig = sigmoid_f(iv);
            float fg = sigmoid_f(fv);
            float gc = tanh_f  (gv);
            float og = sigmoid_f(ov);
            float cc = fg * c_st[rr] + ig * gc;
            c_st[rr] = cc;
            float hh = og * tanh_f(cc);
            unsigned hib = f2bf_rne(hh);
            unsigned lob = ftrunc_bf(hh - bfbits2f(hib));
            hw |= (hib & 0xFFFFu) << (16 * rr);
            lw |= (lob & 0xFFFFu) << (16 * rr);
        }
        hfr_hi[wb][ktw][hdw] = hw;
        hfr_lo[wb][ktw][hdw] = lw;

        __syncthreads();   // h(t+1) visible
    }

    // ---- output head: final h(T) in buf 0 (T even)
    if (tid < MB * OUT_DIM) {
        const int bb = tid / OUT_DIM;
        const int o  = tid % OUT_DIM;
        float s = b_out[o];
        const float* wo = W_out + o * H_DIM;
        #pragma unroll
        for (int u = 0; u < H_DIM; ++u) {
            const int kt = u >> 5, kk = u & 31;
            const int dw = (kk >> 3) * 64 + bb * 4 + ((kk & 7) >> 1);
            const int sh = (u & 1) * 16;
            float h = bfbits2f((hfr_hi[0][kt][dw] >> sh) & 0xFFFFu)
                    + bfbits2f((hfr_lo[0][kt][dw] >> sh) & 0xFFFFu);
            s += h * wo[u];
        }
        out[(size_t)(b0 + bb) * OUT_DIM + o] = s;
    }
}

extern "C" void kernel_launch(void* const* d_in, const int* in_sizes, int n_in,
                              void* d_out, int out_size, void* d_ws, size_t ws_size,
                              hipStream_t stream) {
    const float* x     = (const float*)d_in[0];
    const float* W_ih  = (const float*)d_in[1];
    const float* W_hh  = (const float*)d_in[2];
    const float* b_ih  = (const float*)d_in[3];
    const float* b_hh  = (const float*)d_in[4];
    const float* W_out = (const float*)d_in[5];
    const float* b_out = (const float*)d_in[6];
    float* out = (float*)d_out;

    dim3 grid(B_DIM / MB);    // 256 blocks -> 1 per CU
    dim3 block(NTHREADS);     // 8 waves (2 per SIMD)
    lstm_mfma_kernel<<<grid, block, 0, stream>>>(
        x, W_ih, W_hh, b_ih, b_hh, W_out, b_out, out);
}

// Round 7
// 188.676 us; speedup vs baseline: 1.5931x; 1.5931x over previous
//
#include <hip/hip_runtime.h>

#define I_DIM 28
#define H_DIM 64
#define T_DIM 128
#define B_DIM 4096
#define OUT_DIM 10
#define MB 8          // batch rows per block
#define NTHREADS 256  // 4 waves; wave w owns gate-mtiles {w, w+4, w+8, w+12}
#define LOG2E 1.44269504088896340736f

typedef __attribute__((ext_vector_type(8))) short bf16x8;
typedef __attribute__((ext_vector_type(4))) float f32x4;
typedef __attribute__((ext_vector_type(4))) unsigned u32x4;

__device__ __forceinline__ unsigned f2bf_rne(float f) {
    unsigned u = __builtin_bit_cast(unsigned, f);
    return (u + 0x7FFFu + ((u >> 16) & 1u)) >> 16;
}
__device__ __forceinline__ float bfbits2f(unsigned b16) {
    return __builtin_bit_cast(float, b16 << 16);
}
__device__ __forceinline__ unsigned ftrunc_bf(float f) {
    return __builtin_bit_cast(unsigned, f) >> 16;
}

// weights only: split into hi/lo bf16 fragments (called once at startup)
__device__ __forceinline__ void split_frag(const float* v, bf16x8& hi, bf16x8& lo) {
    unsigned hb[8], lb[8];
    #pragma unroll
    for (int j = 0; j < 8; ++j) {
        hb[j] = f2bf_rne(v[j]);
        float rem = v[j] - bfbits2f(hb[j]);
        lb[j] = ftrunc_bf(rem);
    }
    u32x4 hw, lw;
    #pragma unroll
    for (int i = 0; i < 4; ++i) {
        hw[i] = (hb[2*i+1] << 16) | (hb[2*i] & 0xFFFFu);
        lw[i] = (lb[2*i+1] << 16) | (lb[2*i] & 0xFFFFu);
    }
    hi = __builtin_bit_cast(bf16x8, hw);
    lo = __builtin_bit_cast(bf16x8, lw);
}

// pack 8 floats to rne-bf16, frag dword order
__device__ __forceinline__ u32x4 pack_bf8(const float* v) {
    u32x4 w;
    #pragma unroll
    for (int i = 0; i < 4; ++i)
        w[i] = (f2bf_rne(v[2*i+1]) << 16) | (f2bf_rne(v[2*i]) & 0xFFFFu);
    return w;
}

__device__ __forceinline__ float fast_rcp(float v) { return __builtin_amdgcn_rcpf(v); }
__device__ __forceinline__ float exp2_f(float v)  { return __builtin_amdgcn_exp2f(v); }
// zs = LOG2E * z : sigmoid(z)
__device__ __forceinline__ float sigmoid_s(float zs) {
    return fast_rcp(1.0f + exp2_f(-zs));
}
// zs = LOG2E * z : LOG2E * tanh(z)  (scaled output for c-accumulation)
__device__ __forceinline__ float tanh_gs(float zs) {
    float t = fast_rcp(exp2_f(zs + zs) + 1.0f);
    return fmaf(-2.0f * LOG2E, t, LOG2E);
}
// cs = LOG2E * c : tanh(c)  (true units)
__device__ __forceinline__ float tanh_cs(float cs) {
    float t = fast_rcp(exp2_f(cs + cs) + 1.0f);
    return fmaf(-2.0f, t, 1.0f);
}
// lane i <- lane i-8 within each row of 16 (DPP row_shr:8)
__device__ __forceinline__ float dpp_shr8(float v) {
    int r = __builtin_amdgcn_update_dpp(0, __builtin_bit_cast(int, v),
                                        0x118, 0xF, 0xF, true);
    return __builtin_bit_cast(float, r);
}

#define MFMA(A, B, C) __builtin_amdgcn_mfma_f32_16x16x32_bf16((A), (B), (C), 0, 0, 0)

__global__ __launch_bounds__(NTHREADS, 2)
void lstm_mfma_kernel(const float* __restrict__ x,
                      const float* __restrict__ W_ih,
                      const float* __restrict__ W_hh,
                      const float* __restrict__ b_ih,
                      const float* __restrict__ b_hh,
                      const float* __restrict__ W_out,
                      const float* __restrict__ b_out,
                      float* __restrict__ out)
{
    const int tid  = threadIdx.x;
    const int wv   = tid >> 6;        // wave 0..3
    const int lane = tid & 63;
    const int q    = lane >> 4;       // quad
    const int cm   = lane & 15;
    const int b0   = blockIdx.x * MB;

    // h state, single rne-bf16, B-frag dword order, double-buffered.
    // element h[u][b]: dword 64*(u>>3) + 4*b + ((u&7)>>1), halfword u&1.
    __shared__ __align__(16) unsigned hbuf[2][512];
    // x B-frags for the chunk's two timesteps (single bf16)
    __shared__ __align__(16) unsigned xbuf[2][256];

    // ---- resident A-frags (weights, pre-scaled by LOG2E, hi/lo split):
    // wave w, gate g -> mtile w+4g; A[m=cm][k=q*8+j] = LOG2E*W[16*(w+4g)+cm][k]
    bf16x8 Whh_hi[4][2], Whh_lo[4][2], Wih_hi[4], Wih_lo[4];
    f32x4  bias_c[4];
    #pragma unroll
    for (int g = 0; g < 4; ++g) {
        const int gn = (wv + 4 * g) * 16 + cm;     // global gate row
        #pragma unroll
        for (int kt = 0; kt < 2; ++kt) {
            const float* wr = W_hh + gn * H_DIM + kt * 32 + q * 8;
            float wt[8];
            float4 wa = *(const float4*)wr;
            float4 wb = *(const float4*)(wr + 4);
            wt[0]=wa.x*LOG2E; wt[1]=wa.y*LOG2E; wt[2]=wa.z*LOG2E; wt[3]=wa.w*LOG2E;
            wt[4]=wb.x*LOG2E; wt[5]=wb.y*LOG2E; wt[6]=wb.z*LOG2E; wt[7]=wb.w*LOG2E;
            split_frag(wt, Whh_hi[g][kt], Whh_lo[g][kt]);
        }
        {
            const float* ir = W_ih + gn * I_DIM + q * 8;
            float wt[8];
            float4 ia = *(const float4*)ir;
            wt[0]=ia.x*LOG2E; wt[1]=ia.y*LOG2E; wt[2]=ia.z*LOG2E; wt[3]=ia.w*LOG2E;
            if (q < 3) {
                float4 ib = *(const float4*)(ir + 4);
                wt[4]=ib.x*LOG2E; wt[5]=ib.y*LOG2E; wt[6]=ib.z*LOG2E; wt[7]=ib.w*LOG2E;
            } else { wt[4]=0.f; wt[5]=0.f; wt[6]=0.f; wt[7]=0.f; }
            split_frag(wt, Wih_hi[g], Wih_lo[g]);
        }
        // bias for C rows 4q+r of this mtile: unit u = 16*wv + 4q + r
        #pragma unroll
        for (int r = 0; r < 4; ++r) {
            const int row = g * H_DIM + wv * 16 + 4 * q + r;
            bias_c[g][r] = (b_ih[row] + b_hh[row]) * LOG2E;
        }
    }

    // zero h buffers (cols b=8..15 stay 0 forever)
    for (int i = tid; i < 1024; i += NTHREADS)
        ((unsigned*)hbuf)[i] = 0u;

    // ---- x loader (waves 0,1 handle t = 2*chunk + wv)
    auto load_x = [&](int t, float4& xa, float4& xb) {
        if (cm < MB) {
            const float* p = x + ((size_t)(b0 + cm) * T_DIM + t) * I_DIM + q * 8;
            xa = *(const float4*)p;
            if (q < 3) xb = *(const float4*)(p + 4);
            else       xb = float4{0.f, 0.f, 0.f, 0.f};
        } else {
            xa = float4{0.f, 0.f, 0.f, 0.f};
            xb = float4{0.f, 0.f, 0.f, 0.f};
        }
    };

    float4 xa_cur{0,0,0,0}, xb_cur{0,0,0,0};
    if (wv < 2) load_x(wv, xa_cur, xb_cur);

    float2 c_st = {0.f, 0.f};   // scaled cell state (LOG2E*c) for 2 cells
    const int hdw = 64 * (2 * wv + (q >> 1)) + 4 * (cm & 7)
                  + 2 * (q & 1) + (cm >> 3);   // h write dword

    for (int ch = 0; ch < T_DIM / 2; ++ch) {
        // prefetch next chunk's x, then pack+store current (single bf16)
        float4 xa_nxt{0,0,0,0}, xb_nxt{0,0,0,0};
        if (wv < 2) {
            int tn = 2 * ch + 2 + wv;
            if (tn > T_DIM - 1) tn = T_DIM - 1;
            load_x(tn, xa_nxt, xb_nxt);
            float xt[8];
            xt[0]=xa_cur.x; xt[1]=xa_cur.y; xt[2]=xa_cur.z; xt[3]=xa_cur.w;
            xt[4]=xb_cur.x; xt[5]=xb_cur.y; xt[6]=xb_cur.z; xt[7]=xb_cur.w;
            *(u32x4*)&xbuf[wv][lane * 4] = pack_bf8(xt);
        }
        __syncthreads();   // xbuf visible; also orders prev step-1 h writes

        // xw = (LOG2E*Wih) * x^T + scaled bias, both timesteps (in registers)
        f32x4 xw[2][4];
        #pragma unroll
        for (int tt = 0; tt < 2; ++tt) {
            bf16x8 X = __builtin_bit_cast(bf16x8, *(u32x4*)&xbuf[tt][lane * 4]);
            #pragma unroll
            for (int g = 0; g < 4; ++g) {
                f32x4 a = MFMA(Wih_hi[g], X, bias_c[g]);
                a = MFMA(Wih_lo[g], X, a);
                xw[tt][g] = a;
            }
        }

        // two recurrence steps: tt=0 reads hbuf[0] writes hbuf[1]; tt=1 reverse
        #pragma unroll
        for (int tt = 0; tt < 2; ++tt) {
            const int rb = tt, wb = tt ^ 1;
            if (tt == 1) __syncthreads();   // h(t) writes visible

            bf16x8 H0 = __builtin_bit_cast(bf16x8, *(u32x4*)&hbuf[rb][lane * 4]);
            bf16x8 H1 = __builtin_bit_cast(bf16x8, *(u32x4*)&hbuf[rb][256 + lane * 4]);

            f32x4 acc[4];
            #pragma unroll
            for (int g = 0; g < 4; ++g) {
                f32x4 a = MFMA(Whh_hi[g][0], H0, xw[tt][g]);
                a = MFMA(Whh_hi[g][1], H1, a);
                a = MFMA(Whh_lo[g][0], H0, a);
                a = MFMA(Whh_lo[g][1], H1, a);
                acc[g] = a;
            }

            // redistribute: lanes cm>=8 take rows 2,3 from lane-8
            float gv[4][2];
            #pragma unroll
            for (int g = 0; g < 4; ++g) {
                float a2 = dpp_shr8(acc[g][2]);
                float a3 = dpp_shr8(acc[g][3]);
                gv[g][0] = (cm < 8) ? acc[g][0] : a2;
                gv[g][1] = (cm < 8) ? acc[g][1] : a3;
            }

            // update 2 cells (preacts are LOG2E-scaled); h packed single bf16
            unsigned hw = 0;
            #pragma unroll
            for (int rr = 0; rr < 2; ++rr) {
                float ig = sigmoid_s(gv[0][rr]);
                float fg = sigmoid_s(gv[1][rr]);
                float gs = tanh_gs (gv[2][rr]);     // LOG2E*tanh
                float og = sigmoid_s(gv[3][rr]);
                float cc = fg * (rr ? c_st.y : c_st.x) + ig * gs;  // scaled c
                if (rr) c_st.y = cc; else c_st.x = cc;
                float hh = og * tanh_cs(cc);
                hw |= (f2bf_rne(hh) & 0xFFFFu) << (16 * rr);
            }
            hbuf[wb][hdw] = hw;
        }
        xa_cur = xa_nxt; xb_cur = xb_nxt;
    }

    __syncthreads();

    // ---- output head: final h(T) is in hbuf[0] (T even)
    if (tid < MB * OUT_DIM) {
        const int bb = tid / OUT_DIM;
        const int o  = tid % OUT_DIM;
        float s = b_out[o];
        const float* wo = W_out + o * H_DIM;
        #pragma unroll
        for (int u = 0; u < H_DIM; ++u) {
            const int dw = 64 * (u >> 3) + 4 * bb + ((u & 7) >> 1);
            const int sh = (u & 1) * 16;
            float h = bfbits2f((hbuf[0][dw] >> sh) & 0xFFFFu);
            s += h * wo[u];
        }
        out[(size_t)(b0 + bb) * OUT_DIM + o] = s;
    }
}

extern "C" void kernel_launch(void* const* d_in, const int* in_sizes, int n_in,
                              void* d_out, int out_size, void* d_ws, size_t ws_size,
                              hipStream_t stream) {
    const float* x     = (const float*)d_in[0];
    const float* W_ih  = (const float*)d_in[1];
    const float* W_hh  = (const float*)d_in[2];
    const float* b_ih  = (const float*)d_in[3];
    const float* b_hh  = (const float*)d_in[4];
    const float* W_out = (const float*)d_in[5];
    const float* b_out = (const float*)d_in[6];
    float* out = (float*)d_out;

    dim3 grid(B_DIM / MB);    // 512 blocks -> 2 per CU (antiphase overlap)
    dim3 block(NTHREADS);     // 4 waves
    lstm_mfma_kernel<<<grid, block, 0, stream>>>(
        x, W_ih, W_hh, b_ih, b_hh, W_out, b_out, out);
}

// Round 8
// 168.759 us; speedup vs baseline: 1.7811x; 1.1180x over previous
//
#include <hip/hip_runtime.h>

#define I_DIM 28
#define H_DIM 64
#define T_DIM 128
#define B_DIM 4096
#define OUT_DIM 10
#define MB 8          // batch rows per block
#define NTHREADS 256  // 4 waves; wave w owns gate-mtiles {w, w+4, w+8, w+12}
#define LOG2E 1.44269504088896340736f

typedef __attribute__((ext_vector_type(8))) short bf16x8;
typedef __attribute__((ext_vector_type(4))) float f32x4;
typedef __attribute__((ext_vector_type(4))) unsigned u32x4;

__device__ __forceinline__ float bfbits2f(unsigned b16) {
    return __builtin_bit_cast(float, b16 << 16);
}
// rne-rounded fp32 bits (bf16 lives in top 16 after the add)
__device__ __forceinline__ unsigned rne_u(float f) {
    unsigned u = __builtin_bit_cast(unsigned, f);
    return u + 0x7FFFu + ((u >> 16) & 1u);
}
// pack two floats -> (bf16(b)<<16)|bf16(a) : 2 rne-adds + 1 v_perm
__device__ __forceinline__ unsigned pack_pair(float a, float b) {
    return __builtin_amdgcn_perm(rne_u(b), rne_u(a), 0x07060302u);
}
__device__ __forceinline__ unsigned f2bf_rne(float f) { return rne_u(f) >> 16; }
__device__ __forceinline__ unsigned ftrunc_bf(float f) {
    return __builtin_bit_cast(unsigned, f) >> 16;
}

// 8 floats -> single rne-bf16 frag (4 dwords)
__device__ __forceinline__ bf16x8 pack_frag(const float* v) {
    u32x4 w;
    #pragma unroll
    for (int i = 0; i < 4; ++i) w[i] = pack_pair(v[2*i], v[2*i+1]);
    return __builtin_bit_cast(bf16x8, w);
}

// 8 floats -> hi/lo bf16 frags (used for W_ih only; startup)
__device__ __forceinline__ void split_frag(const float* v, bf16x8& hi, bf16x8& lo) {
    unsigned hb[8], lb[8];
    #pragma unroll
    for (int j = 0; j < 8; ++j) {
        hb[j] = f2bf_rne(v[j]);
        float rem = v[j] - bfbits2f(hb[j]);
        lb[j] = ftrunc_bf(rem);
    }
    u32x4 hw, lw;
    #pragma unroll
    for (int i = 0; i < 4; ++i) {
        hw[i] = (hb[2*i+1] << 16) | (hb[2*i] & 0xFFFFu);
        lw[i] = (lb[2*i+1] << 16) | (lb[2*i] & 0xFFFFu);
    }
    hi = __builtin_bit_cast(bf16x8, hw);
    lo = __builtin_bit_cast(bf16x8, lw);
}

__device__ __forceinline__ float fast_rcp(float v) { return __builtin_amdgcn_rcpf(v); }
__device__ __forceinline__ float exp2_f(float v)  { return __builtin_amdgcn_exp2f(v); }
__device__ __forceinline__ float sigmoid_s(float zs) {           // zs = LOG2E*z
    return fast_rcp(1.0f + exp2_f(-zs));
}
__device__ __forceinline__ float tanh_gs(float zs) {             // LOG2E*tanh(z)
    float t = fast_rcp(exp2_f(zs + zs) + 1.0f);
    return fmaf(-2.0f * LOG2E, t, LOG2E);
}
__device__ __forceinline__ float tanh_cs(float cs) {             // tanh(c), cs=LOG2E*c
    float t = fast_rcp(exp2_f(cs + cs) + 1.0f);
    return fmaf(-2.0f, t, 1.0f);
}
__device__ __forceinline__ float dpp_shr8(float v) {             // lane i <- i-8 (row of 16)
    int r = __builtin_amdgcn_update_dpp(0, __builtin_bit_cast(int, v),
                                        0x118, 0xF, 0xF, true);
    return __builtin_bit_cast(float, r);
}

#define MFMA(A, B, C) __builtin_amdgcn_mfma_f32_16x16x32_bf16((A), (B), (C), 0, 0, 0)

__global__ __launch_bounds__(NTHREADS, 2)
void lstm_mfma_kernel(const float* __restrict__ x,
                      const float* __restrict__ W_ih,
                      const float* __restrict__ W_hh,
                      const float* __restrict__ b_ih,
                      const float* __restrict__ b_hh,
                      const float* __restrict__ W_out,
                      const float* __restrict__ b_out,
                      float* __restrict__ out)
{
    const int tid  = threadIdx.x;
    const int wv   = tid >> 6;        // wave 0..3
    const int lane = tid & 63;
    const int q    = lane >> 4;       // quad
    const int cm   = lane & 15;
    const int b0   = blockIdx.x * MB;

    // h state, single rne-bf16, B-frag dword order, double-buffered.
    __shared__ __align__(16) unsigned hbuf[2][512];
    // x B-frags for the chunk's two timesteps (single bf16)
    __shared__ __align__(16) unsigned xbuf[2][256];

    // ---- resident A-frags (weights, pre-scaled by LOG2E):
    // W_hh single rne-bf16 (2 MFMAs/gate); W_ih hi/lo split (2 MFMAs/gate/tt)
    bf16x8 Whh[4][2], Wih_hi[4], Wih_lo[4];
    f32x4  bias_c[4];
    #pragma unroll
    for (int g = 0; g < 4; ++g) {
        const int gn = (wv + 4 * g) * 16 + cm;     // global gate row
        #pragma unroll
        for (int kt = 0; kt < 2; ++kt) {
            const float* wr = W_hh + gn * H_DIM + kt * 32 + q * 8;
            float wt[8];
            float4 wa = *(const float4*)wr;
            float4 wb = *(const float4*)(wr + 4);
            wt[0]=wa.x*LOG2E; wt[1]=wa.y*LOG2E; wt[2]=wa.z*LOG2E; wt[3]=wa.w*LOG2E;
            wt[4]=wb.x*LOG2E; wt[5]=wb.y*LOG2E; wt[6]=wb.z*LOG2E; wt[7]=wb.w*LOG2E;
            Whh[g][kt] = pack_frag(wt);
        }
        {
            const float* ir = W_ih + gn * I_DIM + q * 8;
            float wt[8];
            float4 ia = *(const float4*)ir;
            wt[0]=ia.x*LOG2E; wt[1]=ia.y*LOG2E; wt[2]=ia.z*LOG2E; wt[3]=ia.w*LOG2E;
            if (q < 3) {
                float4 ib = *(const float4*)(ir + 4);
                wt[4]=ib.x*LOG2E; wt[5]=ib.y*LOG2E; wt[6]=ib.z*LOG2E; wt[7]=ib.w*LOG2E;
            } else { wt[4]=0.f; wt[5]=0.f; wt[6]=0.f; wt[7]=0.f; }
            split_frag(wt, Wih_hi[g], Wih_lo[g]);
        }
        #pragma unroll
        for (int r = 0; r < 4; ++r) {
            const int row = g * H_DIM + wv * 16 + 4 * q + r;
            bias_c[g][r] = (b_ih[row] + b_hh[row]) * LOG2E;
        }
    }

    // zero h buffers (cols b=8..15 stay 0 forever)
    for (int i = tid; i < 1024; i += NTHREADS)
        ((unsigned*)hbuf)[i] = 0u;

    // ---- x pointers (waves 0,1 handle t = 2*chunk + wv), hoisted addressing
    const float* xp = x + ((size_t)(b0 + (cm & 7)) * T_DIM + wv) * I_DIM + q * 8;
    const float* const xp_last = x + ((size_t)(b0 + (cm & 7)) * T_DIM + (T_DIM - 1)) * I_DIM + q * 8;

    auto load_from = [&](const float* p, float4& xa, float4& xb) {
        if (cm < MB) {
            xa = *(const float4*)p;
            if (q < 3) xb = *(const float4*)(p + 4);
            else       xb = float4{0.f, 0.f, 0.f, 0.f};
        } else {
            xa = float4{0.f, 0.f, 0.f, 0.f};
            xb = float4{0.f, 0.f, 0.f, 0.f};
        }
    };

    float4 xa_cur{0,0,0,0}, xb_cur{0,0,0,0};
    if (wv < 2) load_from(xp, xa_cur, xb_cur);

    float2 c_st = {0.f, 0.f};   // scaled cell state (LOG2E*c) for 2 cells
    const int hdw = 64 * (2 * wv + (q >> 1)) + 4 * (cm & 7)
                  + 2 * (q & 1) + (cm >> 3);   // h write dword

    for (int ch = 0; ch < T_DIM / 2; ++ch) {
        // prefetch next chunk's x, then pack+store current (single bf16)
        float4 xa_nxt{0,0,0,0}, xb_nxt{0,0,0,0};
        if (wv < 2) {
            const float* pn = (ch < T_DIM / 2 - 1) ? xp + 2 * I_DIM : xp_last;
            load_from(pn, xa_nxt, xb_nxt);
            xp = pn;
            u32x4 w;
            w[0] = pack_pair(xa_cur.x, xa_cur.y);
            w[1] = pack_pair(xa_cur.z, xa_cur.w);
            w[2] = pack_pair(xb_cur.x, xb_cur.y);
            w[3] = pack_pair(xb_cur.z, xb_cur.w);
            *(u32x4*)&xbuf[wv][lane * 4] = w;
        }
        __syncthreads();   // xbuf visible; also orders prev step-1 h writes

        // xw = (LOG2E*Wih) * x^T + scaled bias, both timesteps (in registers)
        f32x4 xw[2][4];
        #pragma unroll
        for (int tt = 0; tt < 2; ++tt) {
            bf16x8 X = __builtin_bit_cast(bf16x8, *(u32x4*)&xbuf[tt][lane * 4]);
            #pragma unroll
            for (int g = 0; g < 4; ++g) {
                f32x4 a = MFMA(Wih_hi[g], X, bias_c[g]);
                a = MFMA(Wih_lo[g], X, a);
                xw[tt][g] = a;
            }
        }

        // two recurrence steps: tt=0 reads hbuf[0] writes hbuf[1]; tt=1 reverse
        #pragma unroll
        for (int tt = 0; tt < 2; ++tt) {
            const int rb = tt, wb = tt ^ 1;
            if (tt == 1) __syncthreads();   // h(t) writes visible

            bf16x8 H0 = __builtin_bit_cast(bf16x8, *(u32x4*)&hbuf[rb][lane * 4]);
            bf16x8 H1 = __builtin_bit_cast(bf16x8, *(u32x4*)&hbuf[rb][256 + lane * 4]);

            f32x4 acc[4];
            #pragma unroll
            for (int g = 0; g < 4; ++g) {
                f32x4 a = MFMA(Whh[g][0], H0, xw[tt][g]);
                a = MFMA(Whh[g][1], H1, a);
                acc[g] = a;
            }

            // redistribute: lanes cm>=8 take rows 2,3 from lane-8
            float gv[4][2];
            #pragma unroll
            for (int g = 0; g < 4; ++g) {
                float a2 = dpp_shr8(acc[g][2]);
                float a3 = dpp_shr8(acc[g][3]);
                gv[g][0] = (cm < 8) ? acc[g][0] : a2;
                gv[g][1] = (cm < 8) ? acc[g][1] : a3;
            }

            // update 2 cells (preacts are LOG2E-scaled); serial chain -> boost prio
            __builtin_amdgcn_s_setprio(1);
            float h0, h1;
            {
                float ig = sigmoid_s(gv[0][0]);
                float fg = sigmoid_s(gv[1][0]);
                float gs = tanh_gs (gv[2][0]);
                float og = sigmoid_s(gv[3][0]);
                float cc = fmaf(fg, c_st.x, ig * gs);
                c_st.x = cc;
                h0 = og * tanh_cs(cc);
            }
            {
                float ig = sigmoid_s(gv[0][1]);
                float fg = sigmoid_s(gv[1][1]);
                float gs = tanh_gs (gv[2][1]);
                float og = sigmoid_s(gv[3][1]);
                float cc = fmaf(fg, c_st.y, ig * gs);
                c_st.y = cc;
                h1 = og * tanh_cs(cc);
            }
            hbuf[wb][hdw] = pack_pair(h0, h1);
            __builtin_amdgcn_s_setprio(0);
        }
        xa_cur = xa_nxt; xb_cur = xb_nxt;
    }

    __syncthreads();

    // ---- output head: final h(T) is in hbuf[0] (T even)
    if (tid < MB * OUT_DIM) {
        const int bb = tid / OUT_DIM;
        const int o  = tid % OUT_DIM;
        float s = b_out[o];
        const float* wo = W_out + o * H_DIM;
        #pragma unroll
        for (int u = 0; u < H_DIM; ++u) {
            const int dw = 64 * (u >> 3) + 4 * bb + ((u & 7) >> 1);
            const int sh = (u & 1) * 16;
            float h = bfbits2f((hbuf[0][dw] >> sh) & 0xFFFFu);
            s += h * wo[u];
        }
        out[(size_t)(b0 + bb) * OUT_DIM + o] = s;
    }
}

extern "C" void kernel_launch(void* const* d_in, const int* in_sizes, int n_in,
                              void* d_out, int out_size, void* d_ws, size_t ws_size,
                              hipStream_t stream) {
    const float* x     = (const float*)d_in[0];
    const float* W_ih  = (const float*)d_in[1];
    const float* W_hh  = (const float*)d_in[2];
    const float* b_ih  = (const float*)d_in[3];
    const float* b_hh  = (const float*)d_in[4];
    const float* W_out = (const float*)d_in[5];
    const float* b_out = (const float*)d_in[6];
    float* out = (float*)d_out;

    dim3 grid(B_DIM / MB);    // 512 blocks -> 2 per CU (antiphase overlap)
    dim3 block(NTHREADS);     // 4 waves
    lstm_mfma_kernel<<<grid, block, 0, stream>>>(
        x, W_ih, W_hh, b_ih, b_hh, W_out, b_out, out);
}